// Round 8
// baseline (683.697 us; speedup 1.0000x reference)
//
#include <hip/hip_runtime.h>
#include <hip/hip_bf16.h>

typedef __hip_bfloat16 bf16;
typedef unsigned short ush;
typedef __attribute__((ext_vector_type(8))) unsigned short ush8;
typedef __attribute__((ext_vector_type(4))) float f4;

#define IN_CH 32
#define HID 128
#define OUT_CH 32

__device__ __forceinline__ float bf2f(ush u) {
    return __uint_as_float(((unsigned)u) << 16);
}
__device__ __forceinline__ ush f2bf(float f) {
    __hip_bfloat16 b = __float2bfloat16(f);
    return __builtin_bit_cast(ush, b);
}
__device__ __forceinline__ float ldf(const void* __restrict__ p, size_t idx, int isbf16) {
    return isbf16 ? bf2f(((const ush*)p)[idx]) : ((const float*)p)[idx];
}
__device__ __forceinline__ int ld_edge(const int* __restrict__ ei, size_t elem, int wide) {
    return wide ? ei[2 * elem] : ei[elem];
}

// ---------- sniff dtypes: flags[0]=float_is_bf16, flags[1]=edge_is_i64 ----------
__global__ void k_detect(const unsigned short* __restrict__ xraw,
                         const int* __restrict__ ei, int* __restrict__ flags) {
    __shared__ int cnt_exp, any_nz;
    if (threadIdx.x == 0) { cnt_exp = 0; any_nz = 0; }
    __syncthreads();
    int local = 0;
    for (int k = threadIdx.x; k < 4096; k += 256) {
        int e = (xraw[k] >> 7) & 0xFF;
        if (e >= 100 && e <= 140) ++local;
    }
    atomicAdd(&cnt_exp, local);
    for (int k = threadIdx.x; k < 2048; k += 256)
        if (ei[2 * k + 1] != 0) any_nz = 1;   // benign race
    __syncthreads();
    if (threadIdx.x == 0) {
        flags[0] = (cnt_exp > 3500) ? 1 : 0;
        flags[1] = any_nz ? 0 : 1;
    }
}

__global__ void k_count(const int* __restrict__ ei, int n_edges,
                        const int* __restrict__ flags, int* __restrict__ cnt) {
    int e = blockIdx.x * blockDim.x + threadIdx.x;
    if (e >= n_edges) return;
    int w = flags[1];
    atomicAdd(&cnt[ld_edge(ei, (size_t)n_edges + e, w)], 1);
}

// ---------- scan-free CSR region allocation (one atomic per wave) ----------
__global__ __launch_bounds__(256) void k_alloc(const int* __restrict__ cnt, int n,
                                               int* __restrict__ start,
                                               int* __restrict__ cursor,
                                               int* __restrict__ total) {
    int i = blockIdx.x * blockDim.x + threadIdx.x;
    int lane = threadIdx.x & 63;
    int d = (i < n) ? cnt[i] : 0;
    int p = d;
#pragma unroll
    for (int off = 1; off < 64; off <<= 1) {
        int v = __shfl_up(p, off);
        if (lane >= off) p += v;
    }
    int wtot = __shfl(p, 63);
    int base = 0;
    if (lane == 63) base = atomicAdd(total, wtot);
    base = __shfl(base, 63);
    int s = base + p - d;
    if (i < n) { start[i] = s; cursor[i] = s; }
}

__global__ void k_fill(const int* __restrict__ ei, int n_edges,
                       const int* __restrict__ flags,
                       int* __restrict__ cursor, int* __restrict__ csr) {
    int e = blockIdx.x * blockDim.x + threadIdx.x;
    if (e >= n_edges) return;
    int w = flags[1];
    int d = ld_edge(ei, (size_t)n_edges + e, w);
    int s = ld_edge(ei, (size_t)e, w);
    int p = atomicAdd(&cursor[d], 1);
    csr[p] = s;
}

// ==== layer 1: h[i] = relu(mean_j x[j] @ W1l^T + x[i] @ W1r^T + b1), 32 -> 128 ====
// wave handles TWO nodes at once (interleaved gathers = 2x loads in flight).
// lane = (slot 0..15 = edge slot, chunk 0..3 = 8-channel chunk)
__global__ __launch_bounds__(256) void k_l1(
        const void* __restrict__ x,
        const int* __restrict__ start, const int* __restrict__ cnt,
        const int* __restrict__ csr,
        const void* __restrict__ W1l, const void* __restrict__ W1r,
        const void* __restrict__ b1,
        const int* __restrict__ flags,
        ush* __restrict__ hout, int n_nodes, int n_edges) {
    __shared__ ush wst[2 * HID * IN_CH];   // 16 KB: W1l then W1r, bf16 [o][c]
    int fb = flags[0];
    int t = threadIdx.x;
    for (int idx = t; idx < HID * IN_CH; idx += 256) {
        wst[idx]                 = f2bf(ldf(W1l, idx, fb));
        wst[HID * IN_CH + idx]   = f2bf(ldf(W1r, idx, fb));
    }
    __syncthreads();
    int wave = t >> 6, lane = t & 63;
    int slot = lane >> 2;    // 0..15
    int chunk = lane & 3;    // 0..3
    ush8 wlr[8], wrr[8];
    float bsr[8];
#pragma unroll
    for (int j = 0; j < 8; ++j) {
        int o = slot * 8 + j;
        wlr[j] = *(const ush8*)&wst[o * IN_CH + chunk * 8];
        wrr[j] = *(const ush8*)&wst[HID * IN_CH + o * IN_CH + chunk * 8];
        bsr[j] = ldf(b1, o, fb);
    }
    int gw = blockIdx.x * 4 + wave;
    int nw = gridDim.x * 4;
    if (fb) {
        // ---- hot path: bf16, dual-node ----
        const ush* xb = (const ush*)x;
        for (int i0 = gw * 2; i0 < n_nodes; i0 += nw * 2) {
            int i1 = i0 + 1;
            bool has1 = i1 < n_nodes;
            int i1c = has1 ? i1 : i0;
            int beg0 = start[i0], d0 = cnt[i0];
            int beg1 = has1 ? start[i1] : 0;
            int d1 = has1 ? cnt[i1] : 0;
            float acc0[8] = {0,0,0,0,0,0,0,0}, acc1[8] = {0,0,0,0,0,0,0,0};
            int dmax = d0 > d1 ? d0 : d1;
            for (int base = 0; base < dmax; base += 64) {
                int idx0 = csr[min(beg0 + base + lane, n_edges - 1)];
                int idx1 = csr[min(beg1 + base + lane, n_edges - 1)];
                int lim0 = min(64, d0 - base);       // may be <= 0
                int lim1 = min(64, d1 - base);
                int glim = lim0 > lim1 ? lim0 : lim1;
                for (int g = 0; g < glim; g += 16) {
                    int k = g + slot;
                    int s0 = __shfl(idx0, k);
                    int s1 = __shfl(idx1, k);
                    bool ok0 = k < lim0, ok1 = k < lim1;
                    ush8 v0 = *(const ush8*)(xb + (size_t)(ok0 ? s0 : i0)  * IN_CH + chunk * 8);
                    ush8 v1 = *(const ush8*)(xb + (size_t)(ok1 ? s1 : i1c) * IN_CH + chunk * 8);
#pragma unroll
                    for (int j = 0; j < 8; ++j) {
                        acc0[j] += ok0 ? bf2f(v0[j]) : 0.0f;
                        acc1[j] += ok1 ? bf2f(v1[j]) : 0.0f;
                    }
                }
            }
            // prefetch self rows while the shfl-reduce chains run
            ush8 self0 = *(const ush8*)(xb + (size_t)i0  * IN_CH + chunk * 8);
            ush8 self1 = *(const ush8*)(xb + (size_t)i1c * IN_CH + chunk * 8);
#pragma unroll
            for (int j = 0; j < 8; ++j) {
                acc0[j] += __shfl_xor(acc0[j], 4);
                acc1[j] += __shfl_xor(acc1[j], 4);
                acc0[j] += __shfl_xor(acc0[j], 8);
                acc1[j] += __shfl_xor(acc1[j], 8);
                acc0[j] += __shfl_xor(acc0[j], 16);
                acc1[j] += __shfl_xor(acc1[j], 16);
                acc0[j] += __shfl_xor(acc0[j], 32);
                acc1[j] += __shfl_xor(acc1[j], 32);
            }
            // ---- node 0 epilogue ----
            {
                float rdeg = 1.0f / (float)(d0 > 1 ? d0 : 1);
                float po[8];
#pragma unroll
                for (int j = 0; j < 8; ++j) {
                    float s = 0.0f;
#pragma unroll
                    for (int c = 0; c < 8; ++c)
                        s += (acc0[c] * rdeg) * bf2f(wlr[j][c])
                           + bf2f(self0[c])  * bf2f(wrr[j][c]);
                    po[j] = s;
                }
#pragma unroll
                for (int j = 0; j < 8; ++j) {
                    po[j] += __shfl_xor(po[j], 1);
                    po[j] += __shfl_xor(po[j], 2);
                }
                if (chunk == 0) {
                    ush8 ov;
#pragma unroll
                    for (int j = 0; j < 8; ++j) {
                        float v = po[j] + bsr[j];
                        ov[j] = f2bf(v > 0.0f ? v : 0.0f);
                    }
                    *(ush8*)(hout + (size_t)i0 * HID + slot * 8) = ov;
                }
            }
            // ---- node 1 epilogue ----
            if (has1) {
                float rdeg = 1.0f / (float)(d1 > 1 ? d1 : 1);
                float po[8];
#pragma unroll
                for (int j = 0; j < 8; ++j) {
                    float s = 0.0f;
#pragma unroll
                    for (int c = 0; c < 8; ++c)
                        s += (acc1[c] * rdeg) * bf2f(wlr[j][c])
                           + bf2f(self1[c])  * bf2f(wrr[j][c]);
                    po[j] = s;
                }
#pragma unroll
                for (int j = 0; j < 8; ++j) {
                    po[j] += __shfl_xor(po[j], 1);
                    po[j] += __shfl_xor(po[j], 2);
                }
                if (chunk == 0) {
                    ush8 ov;
#pragma unroll
                    for (int j = 0; j < 8; ++j) {
                        float v = po[j] + bsr[j];
                        ov[j] = f2bf(v > 0.0f ? v : 0.0f);
                    }
                    *(ush8*)(hout + (size_t)i1 * HID + slot * 8) = ov;
                }
            }
        }
    } else {
        // ---- cold path: f32 input, single-node (round-7 code) ----
        const float* xb = (const float*)x;
        for (int i = gw; i < n_nodes; i += nw) {
            int beg = start[i], dg = cnt[i], end = beg + dg;
            float acc[8] = {0,0,0,0,0,0,0,0};
            for (int base = beg; base < end; base += 64) {
                int idxv = csr[min(base + lane, n_edges - 1)];
                int lim = min(64, end - base);
                for (int g = 0; g < lim; g += 16) {
                    int k = g + slot;
                    int src = __shfl(idxv, k);
                    bool ok = k < lim;
                    const float* rp = xb + (size_t)(ok ? src : i) * IN_CH + chunk * 8;
                    f4 a0 = *(const f4*)rp;
                    f4 a1 = *(const f4*)(rp + 4);
#pragma unroll
                    for (int j = 0; j < 4; ++j) {
                        acc[j]     += ok ? a0[j] : 0.0f;
                        acc[4 + j] += ok ? a1[j] : 0.0f;
                    }
                }
            }
#pragma unroll
            for (int j = 0; j < 8; ++j) {
                acc[j] += __shfl_xor(acc[j], 4);
                acc[j] += __shfl_xor(acc[j], 8);
                acc[j] += __shfl_xor(acc[j], 16);
                acc[j] += __shfl_xor(acc[j], 32);
            }
            float rdeg = 1.0f / (float)(dg > 1 ? dg : 1);
            float sv[8];
            const float* rp = xb + (size_t)i * IN_CH + chunk * 8;
            f4 a0 = *(const f4*)rp;
            f4 a1 = *(const f4*)(rp + 4);
#pragma unroll
            for (int j = 0; j < 4; ++j) { sv[j] = a0[j]; sv[4 + j] = a1[j]; }
            float po[8];
#pragma unroll
            for (int j = 0; j < 8; ++j) {
                float s = 0.0f;
#pragma unroll
                for (int c = 0; c < 8; ++c)
                    s += (acc[c] * rdeg) * bf2f(wlr[j][c]) + sv[c] * bf2f(wrr[j][c]);
                po[j] = s;
            }
#pragma unroll
            for (int j = 0; j < 8; ++j) {
                po[j] += __shfl_xor(po[j], 1);
                po[j] += __shfl_xor(po[j], 2);
            }
            if (chunk == 0) {
                ush8 ov;
#pragma unroll
                for (int j = 0; j < 8; ++j) {
                    float v = po[j] + bsr[j];
                    ov[j] = f2bf(v > 0.0f ? v : 0.0f);
                }
                *(ush8*)(hout + (size_t)i * HID + slot * 8) = ov;
            }
        }
    }
}

// ==== g = h @ W2l^T (bf16), s = h @ W2r^T + b2 (bf16) — dense, per node ====
__global__ __launch_bounds__(256) void k_g(
        const ush* __restrict__ h,
        const void* __restrict__ W2l, const void* __restrict__ W2r,
        const void* __restrict__ b2,
        const int* __restrict__ flags,
        ush* __restrict__ g, ush* __restrict__ s, int n_nodes) {
    __shared__ ush wst[2 * OUT_CH * HID];  // 16 KB
    int fb = flags[0];
    int t = threadIdx.x;
    for (int idx = t; idx < OUT_CH * HID; idx += 256) {
        wst[idx]                  = f2bf(ldf(W2l, idx, fb));
        wst[OUT_CH * HID + idx]   = f2bf(ldf(W2r, idx, fb));
    }
    __syncthreads();
    int wave = t >> 6, lane = t & 63;
    int slot = lane >> 4;    // 0..3
    int chunk = lane & 15;   // 0..15
    ush8 wlr[8], wrr[8];
    float bsr[8];
#pragma unroll
    for (int j = 0; j < 8; ++j) {
        int o = slot * 8 + j;
        wlr[j] = *(const ush8*)&wst[o * HID + chunk * 8];
        wrr[j] = *(const ush8*)&wst[OUT_CH * HID + o * HID + chunk * 8];
        bsr[j] = ldf(b2, o, fb);
    }
    int gw = blockIdx.x * 4 + wave;
    int nw = gridDim.x * 4;
    for (int i = gw; i < n_nodes; i += nw) {
        ush8 hv = *(const ush8*)(h + (size_t)i * HID + chunk * 8);
        float sv[8];
#pragma unroll
        for (int j = 0; j < 8; ++j) sv[j] = bf2f(hv[j]);
        float pg[8], ps[8];
#pragma unroll
        for (int j = 0; j < 8; ++j) {
            float a = 0.0f, b = 0.0f;
#pragma unroll
            for (int c = 0; c < 8; ++c) {
                a += sv[c] * bf2f(wlr[j][c]);
                b += sv[c] * bf2f(wrr[j][c]);
            }
            pg[j] = a; ps[j] = b;
        }
#pragma unroll
        for (int j = 0; j < 8; ++j) {
            pg[j] += __shfl_xor(pg[j], 1);
            pg[j] += __shfl_xor(pg[j], 2);
            pg[j] += __shfl_xor(pg[j], 4);
            pg[j] += __shfl_xor(pg[j], 8);
            ps[j] += __shfl_xor(ps[j], 1);
            ps[j] += __shfl_xor(ps[j], 2);
            ps[j] += __shfl_xor(ps[j], 4);
            ps[j] += __shfl_xor(ps[j], 8);
        }
        if (chunk == 0) {
            ush8 go, so;
#pragma unroll
            for (int j = 0; j < 8; ++j) {
                go[j] = f2bf(pg[j]);
                so[j] = f2bf(ps[j] + bsr[j]);
            }
            *(ush8*)(g + (size_t)i * OUT_CH + slot * 8) = go;
            *(ush8*)(s + (size_t)i * OUT_CH + slot * 8) = so;
        }
    }
}

// ==== out[i] = mean_j g[j] + s[i] — dual-node 64B-row gather ====
// lane = (slot 0..15 = edge slot, chunk 0..3 = 8-channel chunk)
__global__ __launch_bounds__(256) void k_l2g(
        const ush* __restrict__ g, const ush* __restrict__ s,
        const int* __restrict__ start, const int* __restrict__ cnt,
        const int* __restrict__ csr,
        const int* __restrict__ flags,
        void* __restrict__ out, int n_nodes, int n_edges) {
    int fb = flags[0];
    int t = threadIdx.x;
    int wave = t >> 6, lane = t & 63;
    int slot = lane >> 2;    // 0..15
    int chunk = lane & 3;    // 0..3
    int gw = blockIdx.x * 4 + wave;
    int nw = gridDim.x * 4;
    for (int i0 = gw * 2; i0 < n_nodes; i0 += nw * 2) {
        int i1 = i0 + 1;
        bool has1 = i1 < n_nodes;
        int i1c = has1 ? i1 : i0;
        int beg0 = start[i0], d0 = cnt[i0];
        int beg1 = has1 ? start[i1] : 0;
        int d1 = has1 ? cnt[i1] : 0;
        float acc0[8] = {0,0,0,0,0,0,0,0}, acc1[8] = {0,0,0,0,0,0,0,0};
        int dmax = d0 > d1 ? d0 : d1;
        for (int base = 0; base < dmax; base += 64) {
            int idx0 = csr[min(beg0 + base + lane, n_edges - 1)];
            int idx1 = csr[min(beg1 + base + lane, n_edges - 1)];
            int lim0 = min(64, d0 - base);
            int lim1 = min(64, d1 - base);
            int glim = lim0 > lim1 ? lim0 : lim1;
            for (int gg = 0; gg < glim; gg += 16) {
                int k = gg + slot;
                int s0 = __shfl(idx0, k);
                int s1 = __shfl(idx1, k);
                bool ok0 = k < lim0, ok1 = k < lim1;
                ush8 v0 = *(const ush8*)(g + (size_t)(ok0 ? s0 : i0)  * OUT_CH + chunk * 8);
                ush8 v1 = *(const ush8*)(g + (size_t)(ok1 ? s1 : i1c) * OUT_CH + chunk * 8);
#pragma unroll
                for (int j = 0; j < 8; ++j) {
                    acc0[j] += ok0 ? bf2f(v0[j]) : 0.0f;
                    acc1[j] += ok1 ? bf2f(v1[j]) : 0.0f;
                }
            }
        }
        // prefetch self rows (all lanes; L1-shared) before the shfl chains
        ush8 self0 = *(const ush8*)(s + (size_t)i0  * OUT_CH + chunk * 8);
        ush8 self1 = *(const ush8*)(s + (size_t)i1c * OUT_CH + chunk * 8);
#pragma unroll
        for (int j = 0; j < 8; ++j) {
            acc0[j] += __shfl_xor(acc0[j], 4);
            acc1[j] += __shfl_xor(acc1[j], 4);
            acc0[j] += __shfl_xor(acc0[j], 8);
            acc1[j] += __shfl_xor(acc1[j], 8);
            acc0[j] += __shfl_xor(acc0[j], 16);
            acc1[j] += __shfl_xor(acc1[j], 16);
            acc0[j] += __shfl_xor(acc0[j], 32);
            acc1[j] += __shfl_xor(acc1[j], 32);
        }
        if (slot == 0) {   // lanes 0..3 hold chunk 0..3
            float rdeg0 = 1.0f / (float)(d0 > 1 ? d0 : 1);
            if (fb) {
                ush8 ov;
#pragma unroll
                for (int j = 0; j < 8; ++j)
                    ov[j] = f2bf(acc0[j] * rdeg0 + bf2f(self0[j]));
                *(ush8*)((ush*)out + (size_t)i0 * OUT_CH + chunk * 8) = ov;
            } else {
                float* op = (float*)out + (size_t)i0 * OUT_CH + chunk * 8;
                f4 a0, a1;
#pragma unroll
                for (int j = 0; j < 4; ++j) {
                    a0[j] = acc0[j] * rdeg0 + bf2f(self0[j]);
                    a1[j] = acc0[4 + j] * rdeg0 + bf2f(self0[4 + j]);
                }
                *(f4*)op = a0;
                *(f4*)(op + 4) = a1;
            }
            if (has1) {
                float rdeg1 = 1.0f / (float)(d1 > 1 ? d1 : 1);
                if (fb) {
                    ush8 ov;
#pragma unroll
                    for (int j = 0; j < 8; ++j)
                        ov[j] = f2bf(acc1[j] * rdeg1 + bf2f(self1[j]));
                    *(ush8*)((ush*)out + (size_t)i1 * OUT_CH + chunk * 8) = ov;
                } else {
                    float* op = (float*)out + (size_t)i1 * OUT_CH + chunk * 8;
                    f4 a0, a1;
#pragma unroll
                    for (int j = 0; j < 4; ++j) {
                        a0[j] = acc1[j] * rdeg1 + bf2f(self1[j]);
                        a1[j] = acc1[4 + j] * rdeg1 + bf2f(self1[4 + j]);
                    }
                    *(f4*)op = a0;
                    *(f4*)(op + 4) = a1;
                }
            }
        }
    }
}

extern "C" void kernel_launch(void* const* d_in, const int* in_sizes, int n_in,
                              void* d_out, int out_size, void* d_ws, size_t ws_size,
                              hipStream_t stream) {
    const void* x   = d_in[0];
    const int*  ei  = (const int*)d_in[1];
    const void* W1l = d_in[2];
    const void* W1r = d_in[3];
    const void* b1  = d_in[4];
    const void* W2l = d_in[5];
    const void* W2r = d_in[6];
    const void* b2  = d_in[7];

    int n_nodes = in_sizes[0] / IN_CH;
    int n_edges = in_sizes[1] / 2;

    // ws layout (~46 MB):
    //   [0,256)   flags (2 ints) + total counter (at +128)
    //   cnt (N) | start (N) | cursor (N) | csr (E) | h (N*HID bf16)
    //   | g (N*OUT bf16) | s (N*OUT bf16)
    char* ws = (char*)d_ws;
    size_t o_cnt   = 256;
    size_t o_start = (o_cnt   + (size_t)n_nodes * 4 + 127) & ~(size_t)127;
    size_t o_cur   = (o_start + (size_t)n_nodes * 4 + 127) & ~(size_t)127;
    size_t o_csr   = (o_cur   + (size_t)n_nodes * 4 + 127) & ~(size_t)127;
    size_t o_h     = (o_csr   + (size_t)n_edges * 4 + 255) & ~(size_t)255;
    size_t o_g     = (o_h     + (size_t)n_nodes * HID * 2 + 255) & ~(size_t)255;
    size_t o_s     = (o_g     + (size_t)n_nodes * OUT_CH * 2 + 255) & ~(size_t)255;

    int* flags  = (int*)ws;
    int* total  = (int*)(ws + 128);
    int* cnt    = (int*)(ws + o_cnt);
    int* start  = (int*)(ws + o_start);
    int* cursor = (int*)(ws + o_cur);
    int* csr    = (int*)(ws + o_csr);
    ush* h      = (ush*)(ws + o_h);
    ush* g      = (ush*)(ws + o_g);
    ush* s      = (ush*)(ws + o_s);

    hipMemsetAsync(ws, 0, 256, stream);                          // flags + total
    hipMemsetAsync(cnt, 0, (size_t)n_nodes * 4, stream);

    k_detect<<<1, 256, 0, stream>>>((const unsigned short*)x, ei, flags);
    k_count<<<(n_edges + 255) / 256, 256, 0, stream>>>(ei, n_edges, flags, cnt);
    k_alloc<<<(n_nodes + 255) / 256, 256, 0, stream>>>(cnt, n_nodes, start, cursor, total);
    k_fill<<<(n_edges + 255) / 256, 256, 0, stream>>>(ei, n_edges, flags, cursor, csr);

    k_l1<<<1024, 256, 0, stream>>>(x, start, cnt, csr, W1l, W1r, b1, flags, h, n_nodes, n_edges);
    k_g<<<512, 256, 0, stream>>>(h, W2l, W2r, b2, flags, g, s, n_nodes);
    k_l2g<<<1024, 256, 0, stream>>>(g, s, start, cnt, csr, flags, d_out, n_nodes, n_edges);
}